// Round 17
// baseline (17.899 us; speedup 1.0000x reference)
//
#include <hip/hip_runtime.h>
#include <hip/hip_bf16.h>

#define NE    16
#define INF   512
#define OUTF  512
#define NT    2048
#define OTILE 32          // out-cols per block; W read ONCE total
#define TCH   64          // tokens per chunk (4 t-subtiles x 16)
#define RCAP  256         // per-expert row capacity in ws (cnt=128±11, +11σ safe)

// LDS row strides: row-to-row bank shift = 4 words -> 2 lanes/bank (free)
#define WSTRIDE 516       // f32 elems per W row  (512 + 4)
#define XSTRIDE 520       // bf16 elems per x row (512 + 8)

#define SZ_W   (OTILE * WSTRIDE * 4)            // 66048 B (f32)
#define SZ_X   (TCH * XSTRIDE * 2)              // 66560 B (bf16)
#define SZ_LST ((NT + TCH) * 4)                 // 8448 B
#define SMEM_BYTES (SZ_W + SZ_X + SZ_LST + 64)  // ~138 KB

#define WS_NEED ((size_t)NE * RCAP * INF * 2)   // 4 MB sorted bf16 x

typedef __attribute__((ext_vector_type(4))) float f32x4;
typedef __attribute__((ext_vector_type(8))) short bf16x8;
typedef __attribute__((ext_vector_type(4))) short bf16x4;

__device__ inline unsigned short f2bf(float f) {
    union { __hip_bfloat16 h; unsigned short s; } u;
    u.h = __float2bfloat16(f);
    return u.s;
}

__device__ inline bf16x8 cvt8(f32x4 lo, f32x4 hi) {
    bf16x8 r;
    r[0] = (short)f2bf(lo[0]); r[1] = (short)f2bf(lo[1]);
    r[2] = (short)f2bf(lo[2]); r[3] = (short)f2bf(lo[3]);
    r[4] = (short)f2bf(hi[0]); r[5] = (short)f2bf(hi[1]);
    r[6] = (short)f2bf(hi[2]); r[7] = (short)f2bf(hi[3]);
    return r;
}

__device__ inline bf16x4 cvt4(f32x4 v) {
    bf16x4 r;
    r[0] = (short)f2bf(v[0]); r[1] = (short)f2bf(v[1]);
    r[2] = (short)f2bf(v[2]); r[3] = (short)f2bf(v[3]);
    return r;
}

__device__ inline void gload_lds16(const void* g, void* l) {
    __builtin_amdgcn_global_load_lds(
        (const __attribute__((address_space(1))) void*)g,
        (__attribute__((address_space(3))) void*)l, 16, 0, 0);
}

// ---------------- Kernel 1: expert-sort + bf16 prepack of x into ws ----------------
__global__ __launch_bounds__(256, 4)
void prepack_x(const float* __restrict__ x, const int* __restrict__ idx,
               unsigned short* __restrict__ xs)
{
    __shared__ int s_list[NT];
    __shared__ int s_wcnt[4];
    const int e     = blockIdx.x & 15;
    const int slice = blockIdx.x >> 4;    // 0..15
    const int tid   = threadIdx.x;
    const int lane  = tid & 63;
    const int wv    = tid >> 6;           // 0..3

    unsigned long long masks[8];
    int wtot = 0;
#pragma unroll
    for (int it = 0; it < 8; ++it) {
        const int i = wv * 512 + it * 64 + lane;
        const unsigned long long mk = __ballot(idx[i] == e);
        masks[it] = mk;
        wtot += __popcll(mk);
    }
    if (lane == 0) s_wcnt[wv] = wtot;
    __syncthreads();
    int base = 0;
#pragma unroll
    for (int w = 0; w < 4; ++w) if (w < wv) base += s_wcnt[w];
    const int cnt = s_wcnt[0] + s_wcnt[1] + s_wcnt[2] + s_wcnt[3];
    const unsigned long long below = (1ull << lane) - 1ull;
    int run = base;
#pragma unroll
    for (int it = 0; it < 8; ++it) {
        const unsigned long long mk = masks[it];
        if (mk & (1ull << lane))
            s_list[run + __popcll(mk & below)] = wv * 512 + it * 64 + lane;
        run += __popcll(mk);
    }
    __syncthreads();

    // copy rows slice, slice+16, ... : f32 row -> bf16 sorted row
    for (int r = slice; r < cnt && r < RCAP; r += 16) {
        const int tok = s_list[r];
        const float2 v = *(const float2*)&x[(size_t)tok * INF + tid * 2];
        ushort2 o; o.x = f2bf(v.x); o.y = f2bf(v.y);
        *(ushort2*)&xs[((size_t)e * RCAP + r) * INF + tid * 2] = o;
    }
}

// ---------------- Kernel 2: main MoE GEMM, all staging via global_load_lds ----------------
__global__ __launch_bounds__(512, 2)
void moe_main(const int* __restrict__ idx, const float* __restrict__ W,
              const float* __restrict__ bias, const unsigned short* __restrict__ xs,
              float* __restrict__ out)
{
    extern __shared__ char smem[];
    float*          s_Wf   = (float*)smem;                       // [OTILE][WSTRIDE] f32
    unsigned short* s_X    = (unsigned short*)(smem + SZ_W);     // [TCH][XSTRIDE] bf16
    int*            s_list = (int*)(smem + SZ_W + SZ_X);
    int*            s_wcnt = (int*)(smem + SZ_W + SZ_X + SZ_LST);

    const int b   = blockIdx.x;
    const int e   = b & 15;               // expert; all blocks of e on XCD e%8
    const int o0  = (b >> 4) * OTILE;     // out-tile base
    const int tid = threadIdx.x;
    const int lane = tid & 63;
    const int wid  = tid >> 6;            // 0..7

    // ---- Phase A: idx loads (registers) ----
    int iv[4];
#pragma unroll
    for (int it = 0; it < 4; ++it)
        iv[it] = idx[wid * 256 + it * 64 + lane];

    // ---- Phase B: stage W tile (f32, raw) -> LDS via global_load_lds, 16B/lane ----
    const float* wbase = W + ((size_t)e * OUTF + o0) * INF;   // 32 rows x 512 f32
#pragma unroll
    for (int r2 = 0; r2 < 4; ++r2) {
        const int row = wid * 4 + r2;
        const float* gsrc = wbase + (size_t)row * INF + lane * 4;
        float* ldst = s_Wf + row * WSTRIDE;
        gload_lds16(gsrc, ldst);                // first 1 KB of row
        gload_lds16(gsrc + 256, ldst + 256);    // second 1 KB
    }

    // ---- Phase C: ballot-compaction token list (overlaps W loads) ----
    unsigned long long masks[4];
    int wtot = 0;
#pragma unroll
    for (int it = 0; it < 4; ++it) {
        const unsigned long long mk = __ballot(iv[it] == e);
        masks[it] = mk;
        wtot += __popcll(mk);
    }
    if (lane == 0) s_wcnt[wid] = wtot;
    __syncthreads();                      // s_wcnt ready; W loads drained
    int base = 0;
#pragma unroll
    for (int w = 0; w < 8; ++w) { int c = s_wcnt[w]; if (w < wid) base += c; }
    const int cnt = s_wcnt[0] + s_wcnt[1] + s_wcnt[2] + s_wcnt[3]
                  + s_wcnt[4] + s_wcnt[5] + s_wcnt[6] + s_wcnt[7];
    const unsigned long long below = (1ull << lane) - 1ull;
    int run = base;
#pragma unroll
    for (int it = 0; it < 4; ++it) {
        const unsigned long long mk = masks[it];
        if (mk & (1ull << lane))
            s_list[run + __popcll(mk & below)] = wid * 256 + it * 64 + lane;
        run += __popcll(mk);
    }
    const int cnt_pad = (cnt + TCH - 1) & ~(TCH - 1);
    for (int i = cnt + tid; i < cnt_pad; i += 512) s_list[i] = -1;
    __syncthreads();                      // s_list ready
    if (cnt == 0) return;

    // ---- Wave layout: 8 waves = 4 (token) x 2 (out) sub-tiles of 16 ----
    const int wt = wid >> 1;   // token sub-tile 0..3
    const int wo = wid & 1;    // out   sub-tile 0..1
    const int lr = lane & 15;
    const int q  = lane >> 4;
    const int wrow = wo * 16 + lr;
    const int orow = o0 + wrow;

    // ---- W fragments: LDS f32 -> bf16 registers (once) ----
    bf16x8 bfr[16];
#pragma unroll
    for (int kk = 0; kk < 16; ++kk) {
        f32x4 lo = *(const f32x4*)&s_Wf[wrow * WSTRIDE + kk * 32 + q * 8];
        f32x4 hi = *(const f32x4*)&s_Wf[wrow * WSTRIDE + kk * 32 + q * 8 + 4];
        bfr[kk] = cvt8(lo, hi);
    }
    const float bv = bias[e * OUTF + orow];

    const unsigned short* xsrc = xs + (size_t)e * RCAP * INF;  // sorted bf16 rows

    // ---- Phase D: 64-token chunks; x staged direct-to-LDS (contiguous bf16) ----
    for (int cb = 0; cb < cnt_pad; cb += TCH) {
#pragma unroll
        for (int r2 = 0; r2 < 8; ++r2) {
            const int row = wid * 8 + r2;
            const unsigned short* gsrc = xsrc + (size_t)(cb + row) * INF + lane * 8;
            unsigned short* ldst = s_X + row * XSTRIDE;
            gload_lds16(gsrc, ldst);          // 64 lanes x 16B = full 1 KB row
        }
        __syncthreads();                      // x chunk ready

        f32x4 acc = {0.f, 0.f, 0.f, 0.f};
#pragma unroll
        for (int kk = 0; kk < 16; ++kk) {
            bf16x8 afr = *(const bf16x8*)&s_X[(wt * 16 + lr) * XSTRIDE + kk * 32 + q * 8];
            acc = __builtin_amdgcn_mfma_f32_16x16x32_bf16(afr, bfr[kk], acc, 0, 0, 0);
        }
#pragma unroll
        for (int j = 0; j < 4; ++j) {
            const int tok = s_list[cb + wt * 16 + q * 4 + j];
            if (tok >= 0) out[(size_t)tok * OUTF + orow] = acc[j] + bv;
        }
        __syncthreads();                      // reads done before next stage
    }
}

// ---------------- Fallback (R16, known-good) if ws too small ----------------
#define FB_LSTRIDE 520
#define FB_SZ_W   (OTILE * FB_LSTRIDE * 2)
#define FB_SZ_X   (TCH * FB_LSTRIDE * 2)
#define FB_SZ_LST ((NT + TCH) * 4)
#define FB_SMEM   (FB_SZ_W + FB_SZ_X + FB_SZ_LST + 32)

__global__ __launch_bounds__(512, 2)
void fallback_kernel(const float* __restrict__ x, const int* __restrict__ idx,
                     const float* __restrict__ W, const float* __restrict__ bias,
                     float* __restrict__ out)
{
    extern __shared__ char smem[];
    short* s_W    = (short*)smem;
    short* s_X    = (short*)(smem + FB_SZ_W);
    int*   s_list = (int*)(smem + FB_SZ_W + FB_SZ_X);
    int*   s_wcnt = (int*)(smem + FB_SZ_W + FB_SZ_X + FB_SZ_LST);

    const int b = blockIdx.x;
    const int e = b & 15;
    const int o0 = (b >> 4) * OTILE;
    const int tid = threadIdx.x;
    const int lane = tid & 63;
    const int wid = tid >> 6;

    int iv[4];
#pragma unroll
    for (int it = 0; it < 4; ++it) iv[it] = idx[wid * 256 + it * 64 + lane];

    const float* wbase = W + ((size_t)e * OUTF + o0) * INF;
#pragma unroll
    for (int i = 0; i < 8; ++i) {
        const int li = tid + i * 512;
        f32x4 v = ((const f32x4*)wbase)[li];
        const int fidx = li * 4;
        *(bf16x4*)(&s_W[(fidx >> 9) * FB_LSTRIDE + (fidx & 511)]) = cvt4(v);
    }

    unsigned long long masks[4]; int wtot = 0;
#pragma unroll
    for (int it = 0; it < 4; ++it) {
        const unsigned long long mk = __ballot(iv[it] == e);
        masks[it] = mk; wtot += __popcll(mk);
    }
    if (lane == 0) s_wcnt[wid] = wtot;
    __syncthreads();
    int base = 0;
#pragma unroll
    for (int w = 0; w < 8; ++w) { int c = s_wcnt[w]; if (w < wid) base += c; }
    const int cnt = s_wcnt[0]+s_wcnt[1]+s_wcnt[2]+s_wcnt[3]+s_wcnt[4]+s_wcnt[5]+s_wcnt[6]+s_wcnt[7];
    const unsigned long long below = (1ull << lane) - 1ull;
    int run = base;
#pragma unroll
    for (int it = 0; it < 4; ++it) {
        const unsigned long long mk = masks[it];
        if (mk & (1ull << lane))
            s_list[run + __popcll(mk & below)] = wid * 256 + it * 64 + lane;
        run += __popcll(mk);
    }
    const int cnt_pad = (cnt + TCH - 1) & ~(TCH - 1);
    for (int i = cnt + tid; i < cnt_pad; i += 512) s_list[i] = -1;
    __syncthreads();
    if (cnt == 0) return;

    const int wt = wid >> 1, wo = wid & 1, lr = lane & 15, q = lane >> 4;
    const int orow = o0 + wo * 16 + lr;
    bf16x8 bfr[16];
#pragma unroll
    for (int kk = 0; kk < 16; ++kk)
        bfr[kk] = *(const bf16x8*)(&s_W[(wo * 16 + lr) * FB_LSTRIDE + kk * 32 + q * 8]);
    const float bv = bias[e * OUTF + orow];
    const int slot = tid >> 3, sub = tid & 7;

    for (int cb = 0; cb < cnt_pad; cb += TCH) {
        int tok_s = s_list[cb + slot]; if (tok_s < 0) tok_s = 0;
        const f32x4* xr = (const f32x4*)(x + (size_t)tok_s * INF);
#pragma unroll
        for (int i = 0; i < 16; ++i) {
            f32x4 v = xr[sub + i * 8];
            *(bf16x4*)(&s_X[slot * FB_LSTRIDE + sub * 4 + i * 32]) = cvt4(v);
        }
        __syncthreads();
        f32x4 acc = {0.f, 0.f, 0.f, 0.f};
#pragma unroll
        for (int kk = 0; kk < 16; ++kk) {
            bf16x8 afr = *(const bf16x8*)(&s_X[(wt * 16 + lr) * FB_LSTRIDE + kk * 32 + q * 8]);
            acc = __builtin_amdgcn_mfma_f32_16x16x32_bf16(afr, bfr[kk], acc, 0, 0, 0);
        }
#pragma unroll
        for (int j = 0; j < 4; ++j) {
            const int tok = s_list[cb + wt * 16 + q * 4 + j];
            if (tok >= 0) out[(size_t)tok * OUTF + orow] = acc[j] + bv;
        }
        __syncthreads();
    }
}

extern "C" void kernel_launch(void* const* d_in, const int* in_sizes, int n_in,
                              void* d_out, int out_size, void* d_ws, size_t ws_size,
                              hipStream_t stream) {
    const float* x    = (const float*)d_in[0];
    const int*   idx  = (const int*)d_in[1];
    const float* W    = (const float*)d_in[2];
    const float* bias = (const float*)d_in[3];
    float* out = (float*)d_out;

    if (ws_size >= WS_NEED && d_ws != nullptr) {
        unsigned short* xs = (unsigned short*)d_ws;
        prepack_x<<<dim3(NE * 16), dim3(256), 0, stream>>>(x, idx, xs);
        moe_main<<<dim3(NE * (OUTF / OTILE)), dim3(512), SMEM_BYTES, stream>>>(
            idx, W, bias, xs, out);
    } else {
        fallback_kernel<<<dim3(NE * (OUTF / OTILE)), dim3(512), FB_SMEM, stream>>>(
            x, idx, W, bias, out);
    }
}

// Round 18
// 14.734 us; speedup vs baseline: 1.2148x; 1.2148x over previous
//
#include <hip/hip_runtime.h>
#include <hip/hip_bf16.h>

#define NE    16
#define INF   512
#define OUTF  512
#define NT    2048
#define OTILE 64          // out-cols per block (each wave: 2 o-subtiles)
#define TCH   64          // tokens per chunk -> typical block does ONE chunk
#define NZ    2           // token-chunk split across blocks
#define LSTRIDE 520       // LDS row stride in bf16 elems (512 + 8 pad)

#define SZ_W   (OTILE * LSTRIDE * 2)            // 66560 B
#define SZ_X   (TCH * LSTRIDE * 2)              // 66560 B
#define SZ_LST ((NT + TCH) * 4)                 // 8448 B
#define SMEM_BYTES (SZ_W + SZ_X + SZ_LST + 64)  // ~141.6 KB (1 block/CU)

typedef __attribute__((ext_vector_type(4))) float f32x4;
typedef __attribute__((ext_vector_type(8))) short bf16x8;
typedef __attribute__((ext_vector_type(4))) short bf16x4;

__device__ inline unsigned short f2bf(float f) {
    union { __hip_bfloat16 h; unsigned short s; } u;
    u.h = __float2bfloat16(f);
    return u.s;
}

__device__ inline bf16x4 cvt4(f32x4 v) {
    bf16x4 r;
    r[0] = (short)f2bf(v[0]); r[1] = (short)f2bf(v[1]);
    r[2] = (short)f2bf(v[2]); r[3] = (short)f2bf(v[3]);
    return r;
}

__global__ __launch_bounds__(512, 2)
void switch_linear_kernel(const float* __restrict__ x,
                          const int* __restrict__ idx,
                          const float* __restrict__ W,
                          const float* __restrict__ bias,
                          float* __restrict__ out)
{
    extern __shared__ char smem[];
    short* s_W    = (short*)smem;                      // [OTILE][LSTRIDE] bf16
    short* s_X    = (short*)(smem + SZ_W);             // [TCH][LSTRIDE] bf16
    int*   s_list = (int*)(smem + SZ_W + SZ_X);
    int*   s_wcnt = (int*)(smem + SZ_W + SZ_X + SZ_LST);

    const int b   = blockIdx.x;
    const int e   = b & 15;               // expert; all blocks of e on XCD e%8
    const int oj  = (b >> 4) & 7;         // o-tile index (stagger phase)
    const int o0  = oj * OTILE;
    const int z   = b >> 7;               // token-chunk phase 0..1
    const int tid = threadIdx.x;
    const int lane = tid & 63;
    const int wid  = tid >> 6;            // 0..7

    // ---- Phase A: issue idx loads, then ALL W loads (stay in flight through list build) ----
    int iv[4];
#pragma unroll
    for (int it = 0; it < 4; ++it)
        iv[it] = idx[wid * 256 + it * 64 + lane];

    const float* wbase = W + ((size_t)e * OUTF + o0) * INF;  // 64 rows x 512 f32, contiguous
    f32x4 wreg[16];
#pragma unroll
    for (int i = 0; i < 16; ++i)
        wreg[i] = ((const f32x4*)wbase)[tid + i * 512];

    // ---- Phase B: ballot-compaction token list (W loads in flight) ----
    unsigned long long masks[4];
    int wtot = 0;
#pragma unroll
    for (int it = 0; it < 4; ++it) {
        const unsigned long long mk = __ballot(iv[it] == e);
        masks[it] = mk;
        wtot += __popcll(mk);
    }
    if (lane == 0) s_wcnt[wid] = wtot;
    __syncthreads();
    int base = 0;
#pragma unroll
    for (int w = 0; w < 8; ++w) { int c = s_wcnt[w]; if (w < wid) base += c; }
    const int cnt = s_wcnt[0] + s_wcnt[1] + s_wcnt[2] + s_wcnt[3]
                  + s_wcnt[4] + s_wcnt[5] + s_wcnt[6] + s_wcnt[7];
    const unsigned long long below = (1ull << lane) - 1ull;
    int run = base;
#pragma unroll
    for (int it = 0; it < 4; ++it) {
        const unsigned long long mk = masks[it];
        if (mk & (1ull << lane))
            s_list[run + __popcll(mk & below)] = wid * 256 + it * 64 + lane;
        run += __popcll(mk);
    }
    const int cnt_pad = (cnt + TCH - 1) & ~(TCH - 1);
    for (int i = cnt + tid; i < cnt_pad; i += 512) s_list[i] = -1;

    // ---- W: cvt regs -> LDS (waits W loads; overlapped idx/list latency) ----
#pragma unroll
    for (int i = 0; i < 16; ++i) {
        const int li  = tid + i * 512;
        const int row = li >> 7;
        const int col = (li * 4) & 511;
        *(bf16x4*)(&s_W[row * LSTRIDE + col]) = cvt4(wreg[i]);
    }
    __syncthreads();                      // s_list + s_W ready
    if (cnt == 0) return;

    // ---- Wave layout: 8 waves = 4 (token) x 2 (out-pairs); each wave 16t x 32o ----
    const int wt  = wid >> 1;  // token sub-tile 0..3
    const int wo2 = wid & 1;   // out pair 0..1 -> o-subtiles {2*wo2, 2*wo2+1}
    const int lr  = lane & 15;
    const int q   = lane >> 4;
    const int or0 = o0 + wo2 * 32 + lr;   // and or0+16
    const float bv0 = bias[e * OUTF + or0];
    const float bv1 = bias[e * OUTF + or0 + 16];

    // x-staging: 8 threads per token row (64 rows), 16 f32x4 each (deep window)
    const int slot = tid >> 3;            // 0..63
    const int sub  = tid & 7;

    // chunks for this z: c = z, z+NZ, ... < cnt_pad/TCH
    const int nch = cnt_pad / TCH;
    const int M = (nch - z + NZ - 1) / NZ;
    if (M <= 0) return;
    int m0 = oj % M;

    for (int k = 0; k < M; ++k) {
        int m = m0 + k; if (m >= M) m -= M;
        const int cb = (z + m * NZ) * TCH;

        // ---- stage x: issue all 16 loads, then cvt+write ----
        int tok_s = s_list[cb + slot];
        if (tok_s < 0) tok_s = 0;
        const f32x4* xr = (const f32x4*)(x + (size_t)tok_s * INF);
        f32x4 xreg[16];
#pragma unroll
        for (int i = 0; i < 16; ++i)
            xreg[i] = xr[sub + i * 8];
#pragma unroll
        for (int i = 0; i < 16; ++i)
            *(bf16x4*)(&s_X[slot * LSTRIDE + (sub + i * 8) * 4]) = cvt4(xreg[i]);
        __syncthreads();                  // s_X ready

        // ---- compute: 32 MFMAs/wave (2 out sub-tiles) ----
        f32x4 acc0 = {0.f, 0.f, 0.f, 0.f};
        f32x4 acc1 = {0.f, 0.f, 0.f, 0.f};
#pragma unroll
        for (int kk = 0; kk < 16; ++kk) {
            bf16x8 afr = *(const bf16x8*)(&s_X[(wt * 16 + lr) * LSTRIDE + kk * 32 + q * 8]);
            bf16x8 b0  = *(const bf16x8*)(&s_W[(wo2 * 32 + lr) * LSTRIDE + kk * 32 + q * 8]);
            bf16x8 b1  = *(const bf16x8*)(&s_W[(wo2 * 32 + 16 + lr) * LSTRIDE + kk * 32 + q * 8]);
            acc0 = __builtin_amdgcn_mfma_f32_16x16x32_bf16(afr, b0, acc0, 0, 0, 0);
            acc1 = __builtin_amdgcn_mfma_f32_16x16x32_bf16(afr, b1, acc1, 0, 0, 0);
        }
        // ---- epilogue: D row = q*4+j (token), col = lr ----
#pragma unroll
        for (int j = 0; j < 4; ++j) {
            const int tok = s_list[cb + wt * 16 + q * 4 + j];
            if (tok >= 0) {
                out[(size_t)tok * OUTF + or0]      = acc0[j] + bv0;
                out[(size_t)tok * OUTF + or0 + 16] = acc1[j] + bv1;
            }
        }
        if (k != M - 1) __syncthreads();  // reads done before next restage
    }
}

extern "C" void kernel_launch(void* const* d_in, const int* in_sizes, int n_in,
                              void* d_out, int out_size, void* d_ws, size_t ws_size,
                              hipStream_t stream) {
    const float* x    = (const float*)d_in[0];
    const int*   idx  = (const int*)d_in[1];
    const float* W    = (const float*)d_in[2];
    const float* bias = (const float*)d_in[3];
    float* out = (float*)d_out;

    dim3 grid(NE * (OUTF / OTILE) * NZ);  // 16 x 8 x 2 = 256 blocks
    dim3 block(512);                      // 8 waves, 1 block/CU
    switch_linear_kernel<<<grid, block, SMEM_BYTES, stream>>>(x, idx, W, bias, out);
}

// Round 19
// 13.199 us; speedup vs baseline: 1.3561x; 1.1163x over previous
//
#include <hip/hip_runtime.h>
#include <hip/hip_bf16.h>

#define NE    16
#define INF   512
#define OUTF  512
#define NT    2048
#define OTILE 64          // out-cols per block (4 o-subtiles of 16)
#define TCH   32          // tokens per chunk (2 t-subtiles of 16)
#define NZ    2           // token-chunk split across blocks
#define LSTRIDE 520       // LDS row stride in bf16 elems (512 + 8 pad)

#define SZ_W   (OTILE * LSTRIDE * 2)            // 66560 B
#define SZ_X   (TCH * LSTRIDE * 2)              // 33280 B per buffer (x2)
#define SZ_LST ((NT + TCH) * 4)                 // 8320 B
#define SMEM_BYTES (SZ_W + 2 * SZ_X + SZ_LST + 64)  // ~141.5 KB, 1 block/CU

typedef __attribute__((ext_vector_type(4))) float f32x4;
typedef __attribute__((ext_vector_type(8))) short bf16x8;
typedef __attribute__((ext_vector_type(4))) short bf16x4;

__device__ inline unsigned short f2bf(float f) {
    union { __hip_bfloat16 h; unsigned short s; } u;
    u.h = __float2bfloat16(f);
    return u.s;
}

__device__ inline bf16x4 cvt4(f32x4 v) {
    bf16x4 r;
    r[0] = (short)f2bf(v[0]); r[1] = (short)f2bf(v[1]);
    r[2] = (short)f2bf(v[2]); r[3] = (short)f2bf(v[3]);
    return r;
}

__global__ __launch_bounds__(512, 2)
void switch_linear_kernel(const float* __restrict__ x,
                          const int* __restrict__ idx,
                          const float* __restrict__ W,
                          const float* __restrict__ bias,
                          float* __restrict__ out)
{
    extern __shared__ char smem[];
    short* s_W    = (short*)smem;                          // [OTILE][LSTRIDE]
    short* s_X0   = (short*)(smem + SZ_W);                 // x buffer 0
    short* s_X1   = (short*)(smem + SZ_W + SZ_X);          // x buffer 1
    int*   s_list = (int*)(smem + SZ_W + 2 * SZ_X);
    int*   s_wcnt = (int*)(smem + SZ_W + 2 * SZ_X + SZ_LST);

    const int b   = blockIdx.x;
    const int e   = b & 15;               // expert; all blocks of e on XCD e%8
    const int oj  = (b >> 4) & 7;         // o-tile index (stagger phase)
    const int o0  = oj * OTILE;
    const int z   = b >> 7;               // token-chunk phase 0..1
    const int tid = threadIdx.x;
    const int lane = tid & 63;
    const int wid  = tid >> 6;            // 0..7

    // ---- Phase A: idx loads ----
    int iv[4];
#pragma unroll
    for (int it = 0; it < 4; ++it)
        iv[it] = idx[wid * 256 + it * 64 + lane];

    // ---- Phase B: stage W tile -> LDS bf16 (z-pair opposite half order) ----
    const float* wbase = W + ((size_t)e * OUTF + o0) * INF;  // 64 rows x 512
#pragma unroll
    for (int i = 0; i < 16; ++i) {
        const int ii = z ? ((i + 8) & 15) : i;
        const int li = tid + ii * 512;
        f32x4 v = ((const f32x4*)wbase)[li];
        const int row = li >> 7;
        const int col = (li * 4) & 511;
        *(bf16x4*)(&s_W[row * LSTRIDE + col]) = cvt4(v);
    }

    // ---- Phase C: ballot-compaction token list ----
    unsigned long long masks[4];
    int wtot = 0;
#pragma unroll
    for (int it = 0; it < 4; ++it) {
        const unsigned long long mk = __ballot(iv[it] == e);
        masks[it] = mk;
        wtot += __popcll(mk);
    }
    if (lane == 0) s_wcnt[wid] = wtot;
    __syncthreads();
    int base = 0;
#pragma unroll
    for (int w = 0; w < 8; ++w) { int c = s_wcnt[w]; if (w < wid) base += c; }
    const int cnt = s_wcnt[0] + s_wcnt[1] + s_wcnt[2] + s_wcnt[3]
                  + s_wcnt[4] + s_wcnt[5] + s_wcnt[6] + s_wcnt[7];
    const unsigned long long below = (1ull << lane) - 1ull;
    int run = base;
#pragma unroll
    for (int it = 0; it < 4; ++it) {
        const unsigned long long mk = masks[it];
        if (mk & (1ull << lane))
            s_list[run + __popcll(mk & below)] = wid * 256 + it * 64 + lane;
        run += __popcll(mk);
    }
    const int cnt_pad = (cnt + TCH - 1) & ~(TCH - 1);
    for (int i = cnt + tid; i < cnt_pad; i += 512) s_list[i] = -1;
    __syncthreads();                      // s_list + s_W ready
    if (cnt == 0) return;

    // ---- Wave layout: 8 waves = 2 (token) x 4 (out) sub-tiles of 16 ----
    const int wt = wid >> 2;   // token sub-tile 0..1
    const int wo = wid & 3;    // out   sub-tile 0..3
    const int lr = lane & 15;
    const int q  = lane >> 4;
    const int orow = o0 + wo * 16 + lr;

    // ---- W fragments into REGISTERS (once; 1 ds_read per MFMA later) ----
    bf16x8 bfr[16];
#pragma unroll
    for (int kk = 0; kk < 16; ++kk)
        bfr[kk] = *(const bf16x8*)(&s_W[(wo * 16 + lr) * LSTRIDE + kk * 32 + q * 8]);
    const float bv = bias[e * OUTF + orow];

    // x-staging mapping: 16 threads per token row (32 rows), 8 f32x4/thread
    const int slot = tid >> 4;            // 0..31
    const int sub  = tid & 15;

    const int nch = cnt_pad / TCH;
    const int M = (nch - z + NZ - 1) / NZ;   // chunks for this z
    if (M <= 0) return;
    const int m0 = oj % M;

    // ---- initial stage: chunk j0 -> buf0 ----
    {
        const int cb = (z + m0 * NZ) * TCH;
        int tok_s = s_list[cb + slot];
        if (tok_s < 0) tok_s = 0;
        const f32x4* xr = (const f32x4*)(x + (size_t)tok_s * INF);
        f32x4 xreg[8];
#pragma unroll
        for (int i = 0; i < 8; ++i) xreg[i] = xr[sub + i * 16];
#pragma unroll
        for (int i = 0; i < 8; ++i)
            *(bf16x4*)(&s_X0[slot * LSTRIDE + (sub + i * 16) * 4]) = cvt4(xreg[i]);
    }
    __syncthreads();                      // buf0 published

    f32x4 xreg[8];
    for (int k = 0; k < M; ++k) {
        const int j  = (m0 + k) < M ? (m0 + k) : (m0 + k - M);
        const int cb = (z + j * NZ) * TCH;
        short* cbuf = (k & 1) ? s_X1 : s_X0;
        short* nbuf = (k & 1) ? s_X0 : s_X1;

        // ---- T14: issue next chunk's loads BEFORE compute (latency hides) ----
        const bool more = (k + 1) < M;
        if (more) {
            const int jn  = (m0 + k + 1) < M ? (m0 + k + 1) : (m0 + k + 1 - M);
            const int cbn = (z + jn * NZ) * TCH;
            int tok_s = s_list[cbn + slot];
            if (tok_s < 0) tok_s = 0;
            const f32x4* xr = (const f32x4*)(x + (size_t)tok_s * INF);
#pragma unroll
            for (int i = 0; i < 8; ++i) xreg[i] = xr[sub + i * 16];
        }

        // ---- compute: 16 MFMAs/wave, A from LDS, B from registers ----
        f32x4 acc = {0.f, 0.f, 0.f, 0.f};
#pragma unroll
        for (int kk = 0; kk < 16; ++kk) {
            bf16x8 afr = *(const bf16x8*)(&cbuf[(wt * 16 + lr) * LSTRIDE + kk * 32 + q * 8]);
            acc = __builtin_amdgcn_mfma_f32_16x16x32_bf16(afr, bfr[kk], acc, 0, 0, 0);
        }
        // ---- epilogue ----
#pragma unroll
        for (int j4 = 0; j4 < 4; ++j4) {
            const int tok = s_list[cb + wt * 16 + q * 4 + j4];
            if (tok >= 0) out[(size_t)tok * OUTF + orow] = acc[j4] + bv;
        }

        if (more) {
            __syncthreads();              // drain reads of nbuf (chunk k-1)
#pragma unroll
            for (int i = 0; i < 8; ++i)
                *(bf16x4*)(&nbuf[slot * LSTRIDE + (sub + i * 16) * 4]) = cvt4(xreg[i]);
            __syncthreads();              // publish nbuf
        }
    }
}

extern "C" void kernel_launch(void* const* d_in, const int* in_sizes, int n_in,
                              void* d_out, int out_size, void* d_ws, size_t ws_size,
                              hipStream_t stream) {
    const float* x    = (const float*)d_in[0];
    const int*   idx  = (const int*)d_in[1];
    const float* W    = (const float*)d_in[2];
    const float* bias = (const float*)d_in[3];
    float* out = (float*)d_out;

    dim3 grid(NE * (OUTF / OTILE) * NZ);  // 16 x 8 x 2 = 256 blocks
    dim3 block(512);                      // 8 waves, 1 block/CU
    switch_linear_kernel<<<grid, block, SMEM_BYTES, stream>>>(x, idx, W, bias, out);
}

// Round 20
// 12.993 us; speedup vs baseline: 1.3776x; 1.0159x over previous
//
#include <hip/hip_runtime.h>
#include <hip/hip_bf16.h>

#define NE    16
#define INF   512
#define OUTF  512
#define NT    2048
#define OTILE 32          // out-cols per block (2 o-subtiles of 16)
#define TCH   32          // tokens per chunk (2 t-subtiles of 16)
#define NZ    2           // token-chunk split across blocks
#define LSTRIDE 520       // LDS row stride in bf16 elems (512 + 8 pad)

#define SZ_W   (OTILE * LSTRIDE * 2)            // 33280 B
#define SZ_X   (TCH * LSTRIDE * 2)              // 33280 B
#define SZ_LST ((NT + TCH) * 4)                 // 8320 B
#define SMEM_BYTES (SZ_W + SZ_X + SZ_LST + 64)  // ~75 KB -> 2 blocks/CU

typedef __attribute__((ext_vector_type(4))) float f32x4;
typedef __attribute__((ext_vector_type(8))) short bf16x8;
typedef __attribute__((ext_vector_type(4))) short bf16x4;

__device__ inline unsigned short f2bf(float f) {
    union { __hip_bfloat16 h; unsigned short s; } u;
    u.h = __float2bfloat16(f);
    return u.s;
}

__device__ inline bf16x4 cvt4(f32x4 v) {
    bf16x4 r;
    r[0] = (short)f2bf(v[0]); r[1] = (short)f2bf(v[1]);
    r[2] = (short)f2bf(v[2]); r[3] = (short)f2bf(v[3]);
    return r;
}

__global__ __launch_bounds__(256, 2)
void switch_linear_kernel(const float* __restrict__ x,
                          const int* __restrict__ idx,
                          const float* __restrict__ W,
                          const float* __restrict__ bias,
                          float* __restrict__ out)
{
    extern __shared__ char smem[];
    short* s_W    = (short*)smem;                      // [OTILE][LSTRIDE]
    short* s_X    = (short*)(smem + SZ_W);             // [TCH][LSTRIDE]
    int*   s_list = (int*)(smem + SZ_W + SZ_X);
    int*   s_wcnt = (int*)(smem + SZ_W + SZ_X + SZ_LST);

    const int b   = blockIdx.x;
    const int e   = b & 15;               // expert; all blocks of e on XCD e%8
    const int oj  = (b >> 4) & 15;        // o-tile index (stagger phase)
    const int o0  = oj * OTILE;
    const int z   = b >> 8;               // token-chunk phase 0..1
    const int tid = threadIdx.x;
    const int lane = tid & 63;
    const int wv   = tid >> 6;            // 0..3

    // ---- Phase A: idx loads (8 iters/thread at 256 threads) ----
    int iv[8];
#pragma unroll
    for (int it = 0; it < 8; ++it)
        iv[it] = idx[wv * 512 + it * 64 + lane];

    // ---- Phase B: stage W tile (32 rows x 512 f32, contiguous) -> LDS bf16 ----
    const float* wbase = W + ((size_t)e * OUTF + o0) * INF;
#pragma unroll
    for (int i = 0; i < 16; ++i) {
        const int li = tid + i * 256;            // f32x4 index, 0..4095
        f32x4 v = ((const f32x4*)wbase)[li];
        const int row = li >> 7;
        const int col = (li * 4) & 511;
        *(bf16x4*)(&s_W[row * LSTRIDE + col]) = cvt4(v);
    }

    // ---- Phase C: ballot-compaction token list ----
    unsigned long long masks[8];
    int wtot = 0;
#pragma unroll
    for (int it = 0; it < 8; ++it) {
        const unsigned long long mk = __ballot(iv[it] == e);
        masks[it] = mk;
        wtot += __popcll(mk);
    }
    if (lane == 0) s_wcnt[wv] = wtot;
    __syncthreads();
    int base = 0;
#pragma unroll
    for (int w = 0; w < 4; ++w) { int c = s_wcnt[w]; if (w < wv) base += c; }
    const int cnt = s_wcnt[0] + s_wcnt[1] + s_wcnt[2] + s_wcnt[3];
    const unsigned long long below = (1ull << lane) - 1ull;
    int run = base;
#pragma unroll
    for (int it = 0; it < 8; ++it) {
        const unsigned long long mk = masks[it];
        if (mk & (1ull << lane))
            s_list[run + __popcll(mk & below)] = wv * 512 + it * 64 + lane;
        run += __popcll(mk);
    }
    const int cnt_pad = (cnt + TCH - 1) & ~(TCH - 1);
    for (int i = cnt + tid; i < cnt_pad; i += 256) s_list[i] = -1;
    __syncthreads();                      // s_list + s_W ready
    if (cnt == 0) return;

    // ---- Wave layout: 4 waves = 2 (token) x 2 (out) sub-tiles of 16 ----
    const int wt = wv >> 1;    // token sub-tile 0..1
    const int wo = wv & 1;     // out   sub-tile 0..1
    const int lr = lane & 15;
    const int q  = lane >> 4;
    const int orow = o0 + wo * 16 + lr;

    // ---- W fragments into REGISTERS (once) ----
    bf16x8 bfr[16];
#pragma unroll
    for (int kk = 0; kk < 16; ++kk)
        bfr[kk] = *(const bf16x8*)(&s_W[(wo * 16 + lr) * LSTRIDE + kk * 32 + q * 8]);
    const float bv = bias[e * OUTF + orow];

    // x-staging mapping: 8 threads per token row (32 rows), 16 f32x4/thread
    const int slot = tid >> 3;            // 0..31
    const int sub  = tid & 7;

    const int nch = cnt_pad / TCH;
    const int M = (nch - z + NZ - 1) / NZ;
    if (M <= 0) return;
    const int m0 = oj % M;

    for (int k = 0; k < M; ++k) {
        int m = m0 + k; if (m >= M) m -= M;
        const int cb = (z + m * NZ) * TCH;

        int tok_s = s_list[cb + slot];
        if (tok_s < 0) tok_s = 0;
        const f32x4* xr = (const f32x4*)(x + (size_t)tok_s * INF);
        f32x4 xreg[16];
#pragma unroll
        for (int i = 0; i < 16; ++i) xreg[i] = xr[sub + i * 8];
#pragma unroll
        for (int i = 0; i < 16; ++i)
            *(bf16x4*)(&s_X[slot * LSTRIDE + (sub + i * 8) * 4]) = cvt4(xreg[i]);
        __syncthreads();                  // s_X ready

        f32x4 acc = {0.f, 0.f, 0.f, 0.f};
#pragma unroll
        for (int kk = 0; kk < 16; ++kk) {
            bf16x8 afr = *(const bf16x8*)(&s_X[(wt * 16 + lr) * LSTRIDE + kk * 32 + q * 8]);
            acc = __builtin_amdgcn_mfma_f32_16x16x32_bf16(afr, bfr[kk], acc, 0, 0, 0);
        }
#pragma unroll
        for (int j = 0; j < 4; ++j) {
            const int tok = s_list[cb + wt * 16 + q * 4 + j];
            if (tok >= 0) out[(size_t)tok * OUTF + orow] = acc[j] + bv;
        }
        if (k != M - 1) __syncthreads();  // reads done before next restage
    }
}

extern "C" void kernel_launch(void* const* d_in, const int* in_sizes, int n_in,
                              void* d_out, int out_size, void* d_ws, size_t ws_size,
                              hipStream_t stream) {
    const float* x    = (const float*)d_in[0];
    const int*   idx  = (const int*)d_in[1];
    const float* W    = (const float*)d_in[2];
    const float* bias = (const float*)d_in[3];
    float* out = (float*)d_out;

    dim3 grid(NE * 16 * NZ);   // 16 e x 16 o-tiles x 2 z = 512 blocks, 2/CU
    dim3 block(256);           // 4 waves
    switch_linear_kernel<<<grid, block, SMEM_BYTES, stream>>>(x, idx, W, bias, out);
}